// Round 1
// baseline (241.522 us; speedup 1.0000x reference)
//
#include <hip/hip_runtime.h>

#define N_NODES 100000
#define N_EDGES 2000000

typedef __bf16 bf16x8 __attribute__((ext_vector_type(8)));
typedef unsigned short us8 __attribute__((ext_vector_type(8)));
typedef float f32x4 __attribute__((ext_vector_type(4)));

__device__ __forceinline__ unsigned short f2bf(float f) {
  // round-to-nearest-even fp32 -> bf16 (inputs are finite, no NaN handling needed)
  unsigned int u = __builtin_bit_cast(unsigned int, f);
  u += 0x7FFFu + ((u >> 16) & 1u);
  return (unsigned short)(u >> 16);
}
__device__ __forceinline__ float bf2f(unsigned short h) {
  unsigned int u = ((unsigned int)h) << 16;
  return __builtin_bit_cast(float, u);
}

// ---------------------------------------------------------------------------
// Node MLP: H = relu(relu(X@W1+b1)@W2+b2), stored as bf16 row-major (N x 64).
// One thread per node; h1[64] lives in registers; W1/W2/b* indices are
// wave-uniform -> scalar loads. Stores packed 2 x bf16 per dword.
// ---------------------------------------------------------------------------
__global__ __launch_bounds__(256) void node_mlp_kernel(
    const float* __restrict__ X, const float* __restrict__ W1,
    const float* __restrict__ b1, const float* __restrict__ W2,
    const float* __restrict__ b2, unsigned short* __restrict__ H) {
  int n = blockIdx.x * 256 + threadIdx.x;
  if (n >= N_NODES) return;
  float4 xv = ((const float4*)X)[n];
  float h1[64];
#pragma unroll
  for (int k = 0; k < 64; ++k) {
    float a = b1[k] + xv.x * W1[k] + xv.y * W1[64 + k] + xv.z * W1[128 + k] +
              xv.w * W1[192 + k];
    h1[k] = fmaxf(a, 0.f);
  }
  unsigned int* Hp = (unsigned int*)(H + n * 64);
#pragma unroll 1
  for (int j = 0; j < 64; j += 2) {
    float a0 = b2[j], a1 = b2[j + 1];
#pragma unroll
    for (int k = 0; k < 64; ++k) {
      a0 += h1[k] * W2[k * 64 + j];
      a1 += h1[k] * W2[k * 64 + j + 1];
    }
    a0 = fmaxf(a0, 0.f);
    a1 = fmaxf(a1, 0.f);
    Hp[j >> 1] = (unsigned int)f2bf(a0) | ((unsigned int)f2bf(a1) << 16);
  }
}

// ---------------------------------------------------------------------------
// Edge MLP: scores = relu(E@We1+be1)@We2 + be2, E=[hu,hv,|hu-hv|] (192 wide).
// One wave computes 16 edges per tile via mfma_f32_16x16x32_bf16:
//   A-frag: lane l holds A[m=l&15][k=(l>>4)*8+j], j=0..7
//   B-frag: lane l holds B[k=(l>>4)*8+j][n=l&15]
//   C/D   : lane l, reg r holds D[row=(l>>4)*4+r][col=l&15]
// We1 B-fragments (6 k-chunks x 4 n-tiles) are loaded ONCE per wave and kept
// in registers (~96 VGPRs) -> the tile loop has no LDS and no weight reloads.
// |hu-hv| A-frags are computed elementwise from the hu/hv frags in registers.
// Layer 2 done in C-layout: per-lane relu+dot partial, shfl_xor butterfly
// over the 16 lanes of each quad group, lanes l15<4 store 16 contiguous
// floats per tile.
// ---------------------------------------------------------------------------
__global__ __launch_bounds__(256) void edge_mlp_kernel(
    const unsigned short* __restrict__ H, const int* __restrict__ pairs,
    const float* __restrict__ We1, const float* __restrict__ be1,
    const float* __restrict__ We2, const float* __restrict__ be2,
    float* __restrict__ out) {
  const int lane = threadIdx.x & 63;
  const int l15 = lane & 15;
  const int quad = lane >> 4;
  const int wid = blockIdx.x * 4 + (threadIdx.x >> 6);
  const int nw = gridDim.x * 4;

  // Persistent B fragments for We1 (fp32 -> bf16 RNE), one-time setup.
  bf16x8 bfrag[6][4];
#pragma unroll
  for (int c = 0; c < 6; ++c) {
#pragma unroll
    for (int jt = 0; jt < 4; ++jt) {
      us8 t;
#pragma unroll
      for (int jj = 0; jj < 8; ++jj)
        t[jj] = f2bf(We1[(c * 32 + quad * 8 + jj) * 64 + jt * 16 + l15]);
      bfrag[c][jt] = __builtin_bit_cast(bf16x8, t);
    }
  }
  float be1v[4], we2v[4];
#pragma unroll
  for (int jt = 0; jt < 4; ++jt) {
    be1v[jt] = be1[jt * 16 + l15];
    we2v[jt] = We2[jt * 16 + l15];
  }
  const float be2v = be2[0];

  const int ntiles = N_EDGES / 16;
  for (int tile = wid; tile < ntiles; tile += nw) {
    const int e = tile * 16 + l15;
    const int u = pairs[2 * e];
    const int v = pairs[2 * e + 1];
    // 16B gathers: chunk c=0 covers k in [0,32), c=1 covers [32,64)
    const us8* pu = (const us8*)(H + u * 64 + quad * 8);
    const us8* pv = (const us8*)(H + v * 64 + quad * 8);
    us8 hu0 = pu[0], hu1 = pu[4];
    us8 hv0 = pv[0], hv1 = pv[4];
    us8 ab0, ab1;
#pragma unroll
    for (int i = 0; i < 8; ++i) {
      ab0[i] = f2bf(fabsf(bf2f(hu0[i]) - bf2f(hv0[i])));
      ab1[i] = f2bf(fabsf(bf2f(hu1[i]) - bf2f(hv1[i])));
    }
    bf16x8 a[6];
    a[0] = __builtin_bit_cast(bf16x8, hu0);
    a[1] = __builtin_bit_cast(bf16x8, hu1);
    a[2] = __builtin_bit_cast(bf16x8, hv0);
    a[3] = __builtin_bit_cast(bf16x8, hv1);
    a[4] = __builtin_bit_cast(bf16x8, ab0);
    a[5] = __builtin_bit_cast(bf16x8, ab1);

    f32x4 acc[4];
#pragma unroll
    for (int jt = 0; jt < 4; ++jt) acc[jt] = (f32x4){0.f, 0.f, 0.f, 0.f};
#pragma unroll
    for (int c = 0; c < 6; ++c) {
#pragma unroll
      for (int jt = 0; jt < 4; ++jt)
        acc[jt] =
            __builtin_amdgcn_mfma_f32_16x16x32_bf16(a[c], bfrag[c][jt],
                                                    acc[jt], 0, 0, 0);
    }

    // Layer 2 + reduction. Lane holds col n=jt*16+l15, rows quad*4+r.
    float p[4];
#pragma unroll
    for (int r = 0; r < 4; ++r) {
      float s = 0.f;
#pragma unroll
      for (int jt = 0; jt < 4; ++jt) {
        float t = acc[jt][r] + be1v[jt];
        s += fmaxf(t, 0.f) * we2v[jt];
      }
      s += __shfl_xor(s, 1);
      s += __shfl_xor(s, 2);
      s += __shfl_xor(s, 4);
      s += __shfl_xor(s, 8);
      p[r] = s;
    }
    if (l15 < 4) {
      float val = p[0];
      val = (l15 == 1) ? p[1] : val;
      val = (l15 == 2) ? p[2] : val;
      val = (l15 == 3) ? p[3] : val;
      out[tile * 16 + quad * 4 + l15] = val + be2v;
    }
  }
}

extern "C" void kernel_launch(void* const* d_in, const int* in_sizes, int n_in,
                              void* d_out, int out_size, void* d_ws,
                              size_t ws_size, hipStream_t stream) {
  const float* X = (const float*)d_in[0];
  const int* pairs = (const int*)d_in[1];
  const float* W1 = (const float*)d_in[2];
  const float* b1 = (const float*)d_in[3];
  const float* W2 = (const float*)d_in[4];
  const float* b2 = (const float*)d_in[5];
  const float* We1 = (const float*)d_in[6];
  const float* be1 = (const float*)d_in[7];
  const float* We2 = (const float*)d_in[8];
  const float* be2 = (const float*)d_in[9];
  float* out = (float*)d_out;
  unsigned short* H = (unsigned short*)d_ws;  // 100000*64 bf16 = 12.8 MB

  node_mlp_kernel<<<(N_NODES + 255) / 256, 256, 0, stream>>>(X, W1, b1, W2, b2,
                                                             H);
  edge_mlp_kernel<<<1024, 256, 0, stream>>>(H, pairs, We1, be1, We2, be2, out);
}